// Round 1
// baseline (1784.663 us; speedup 1.0000x reference)
//
#include <hip/hip_runtime.h>

// LSTM: SEQ=512, B=64, IN=256, H=512, fp32 in/out; bf16 MFMA compute.
// 4 batch-groups x 16 H-slice blocks (32 hid x 4 gates), persistent, 512 steps.
//
// Cross-block h exchange (NEW): self-certifying 16B chunks in d_ws.
//   chunk = [4 x bf16 h | uint tag=t+1 | pad], double-buffered by (t&1).
//   Producer: single global_store_dwordx4 sc0 sc1 (write-through, one packet,
//   tag travels with data -> no flag, no producer vmcnt drain, no atomic RMW).
//   Consumer: poll global_load_dwordx4 sc0 sc1 until all 4 tags == t+1; the
//   poll loads ARE the data loads (one MALL round trip total).
//   2-slot reuse is safe: a block writes slot p for step t only after all
//   blocks consumed step t-1 (same slot), proven by tag visibility ordering.
// Barriers: LDS-only (lgkmcnt(0)+s_barrier) -> no implicit vmcnt(0) drains;
// 2 barriers/step (xfrag staged before A; prev-C drained its readers).
// x(t+2) prefetch issued at top of iter so HBM latency hides under MFMA+ptwise.
// h_seq 'out' writes are plain cached stores (no longer used for exchange).

#define T_STEPS 512
#define BATCH   64
#define IN_D    256
#define HID     512
#define NGROUP  4
#define NSLICE  16
#define BLK_B   16
#define BLK_H   32
#define THREADS 512
#define CH_ROW  128                                 // 16B chunks per (group,row): 512 hid / 4
#define SLOT_BYTES (NGROUP * BLK_B * CH_ROW * 16)   // 131072 B per slot
#define EXCH_INTS  (2 * SLOT_BYTES / 4)             // 65536 dwords total (256 KB)

using short8  = __attribute__((ext_vector_type(8))) short;
using int4v   = __attribute__((ext_vector_type(4))) int;
using float4v = __attribute__((ext_vector_type(4))) float;

#define FRAG_ADDR(f) (((f) << 4) + (((f) >> 4) << 4))   // 16B frag + 16B pad per 16 frags

__device__ __forceinline__ unsigned short f2bf(float f) {
    union { float f; unsigned int i; } v; v.f = f;
    unsigned int r = v.i + 0x7fff + ((v.i >> 16) & 1);
    return (unsigned short)(r >> 16);
}
__device__ __forceinline__ short8 pack8(float4 a, float4 b) {
    short8 s;
    s[0]=(short)f2bf(a.x); s[1]=(short)f2bf(a.y); s[2]=(short)f2bf(a.z); s[3]=(short)f2bf(a.w);
    s[4]=(short)f2bf(b.x); s[5]=(short)f2bf(b.y); s[6]=(short)f2bf(b.z); s[7]=(short)f2bf(b.w);
    return s;
}
__device__ __forceinline__ float sigm(float v) { return 1.0f / (1.0f + __expf(-v)); }
__device__ __forceinline__ float tanh_(float v) { return 2.0f / (1.0f + __expf(-2.0f * v)) - 1.0f; }

// LDS-visibility barrier WITHOUT the vmcnt(0) drain of __syncthreads.
__device__ __forceinline__ void lds_barrier() {
    asm volatile("s_waitcnt lgkmcnt(0)" ::: "memory");
    __builtin_amdgcn_s_barrier();
    __builtin_amdgcn_sched_barrier(0);   // rule 18: no hoist of ds ops above barrier
}

__global__ __launch_bounds__(256, 1) void lstm_init_ws(unsigned int* w, int n) {
    int i = blockIdx.x * blockDim.x + threadIdx.x;
    if (i < n) __hip_atomic_store(&w[i], 0u, __ATOMIC_RELAXED, __HIP_MEMORY_SCOPE_AGENT);
}

__global__ __launch_bounds__(THREADS, 1) void lstm_persist(
    const float* __restrict__ x,
    const float* __restrict__ h0,
    const float* __restrict__ c0,
    const float* __restrict__ Wf, const float* __restrict__ Wfb,
    const float* __restrict__ Uf, const float* __restrict__ Ufb,
    const float* __restrict__ Wi, const float* __restrict__ Wib,
    const float* __restrict__ Ui, const float* __restrict__ Uib,
    const float* __restrict__ Wo, const float* __restrict__ Wob,
    const float* __restrict__ Uo, const float* __restrict__ Uob,
    const float* __restrict__ Wc, const float* __restrict__ Wcb,
    const float* __restrict__ Uc, const float* __restrict__ Ucb,
    float* out,                 // h_seq (T,B,H) | h (B,H) | c (B,H), fp32
    unsigned char* exch)        // [2 slots][NGROUP][16 rows][128 chunks][16B]
{
    __shared__ __attribute__((aligned(16))) unsigned char hfrag[17392]; // 1024 frags
    __shared__ __attribute__((aligned(16))) unsigned char xfrag[8688];  // 512 frags
    __shared__ float g_lds[8 * 256];                                    // gate outputs

    const int tid  = threadIdx.x;
    const int lane = tid & 63;
    const int wave = tid >> 6;            // 0..7
    const int gate = wave >> 1;           // 0:f 1:i 2:o 3:c
    const int hlf  = wave & 1;            // 16-hid half of the 32
    const int grp  = blockIdx.x & 3;      // batch group
    const int slc  = blockIdx.x >> 2;     // hid slice
    const int bb   = grp * BLK_B;
    const int hbase= slc * BLK_H;
    const int lm   = lane & 15;
    const int lq   = lane >> 4;
    const int row  = tid >> 5;            // 0..15 (batch within group)
    const int seg  = tid & 31;            // 0..31

    const float* Ug  = (gate == 0) ? Uf : (gate == 1) ? Ui : (gate == 2) ? Uo : Uc;
    const float* Wg  = (gate == 0) ? Wf : (gate == 1) ? Wi : (gate == 2) ? Wo : Wc;
    const float* Wbg = (gate == 0) ? Wfb : (gate == 1) ? Wib : (gate == 2) ? Wob : Wcb;
    const float* Ubg = (gate == 0) ? Ufb : (gate == 1) ? Uib : (gate == 2) ? Uob : Ucb;
    const int ng = hbase + hlf * 16 + lm;   // lane's gate-output row (B-op n)

    // ---- register-resident bf16 weight fragments ----
    short8 ufrag[16];
#pragma unroll
    for (int ks = 0; ks < 16; ++ks) {
        const float* p = Ug + (size_t)ng * HID + ks * 32 + lq * 8;
        ufrag[ks] = pack8(*(const float4*)(p), *(const float4*)(p + 4));
    }
    short8 wfrag[8];
#pragma unroll
    for (int ks = 0; ks < 8; ++ks) {
        const float* p = Wg + (size_t)ng * IN_D + ks * 32 + lq * 8;
        wfrag[ks] = pack8(*(const float4*)(p), *(const float4*)(p + 4));
    }
    const float bias = Wbg[ng] + Ubg[ng];

    // ---- cell state in registers: thread (row,seg) owns c[row][hbase+seg] ----
    float c_reg = c0[(size_t)(bb + row) * HID + hbase + seg];

    // ---- stage h0 (2 frags/thread) and x0 (1 frag/thread) ----
    {
        const float* ph = h0 + (size_t)(bb + row) * HID + seg * 16;
        int f0 = (seg >> 1) * 64 + (seg & 1) * 32 + row;
        *(short8*)(hfrag + FRAG_ADDR(f0))      = pack8(*(const float4*)(ph),     *(const float4*)(ph + 4));
        *(short8*)(hfrag + FRAG_ADDR(f0 + 16)) = pack8(*(const float4*)(ph + 8), *(const float4*)(ph + 12));

        const float* px = x + (size_t)(bb + row) * IN_D + seg * 8;
        int fx = (seg >> 2) * 64 + (seg & 3) * 16 + row;
        *(short8*)(xfrag + FRAG_ADDR(fx)) = pack8(*(const float4*)(px), *(const float4*)(px + 4));
    }
    // prefetch x_1
    float4 xn0, xn1;
    {
        const float* px = x + ((size_t)1 * BATCH + bb + row) * IN_D + seg * 8;
        xn0 = *(const float4*)(px); xn1 = *(const float4*)(px + 4);
    }
    __syncthreads();

    // accx = bias + x_0 @ W^T
    float4v accx0 = {bias, bias, bias, bias};
    float4v accx1 = {0.f, 0.f, 0.f, 0.f};
#pragma unroll
    for (int ks = 0; ks < 8; ++ks) {
        short8 a = *(const short8*)(xfrag + FRAG_ADDR(ks * 64 + lane));
        if (ks & 1) accx1 = __builtin_amdgcn_mfma_f32_16x16x32_bf16(a, wfrag[ks], accx1, 0, 0, 0);
        else        accx0 = __builtin_amdgcn_mfma_f32_16x16x32_bf16(a, wfrag[ks], accx0, 0, 0, 0);
    }

    float* const out_h = out + (size_t)T_STEPS * BATCH * HID;
    float* const out_c = out_h + (size_t)BATCH * HID;

    // per-thread exchange addresses (slot offset added per step)
    unsigned char* const ex_wr = exch
        + (size_t)((grp * BLK_B + row) * CH_ROW + slc * 8 + (seg >> 2)) * 16;
    unsigned char* const ex_rd = exch
        + (size_t)((grp * BLK_B + row) * CH_ROW + seg * 4) * 16;

    for (int t = 0; t < T_STEPS; ++t) {
        // ---- prefetch x(t+2) early: latency hides under MFMA + pointwise ----
        float4 xm0, xm1;
        {
            int tn = (t + 2 < T_STEPS) ? (t + 2) : (T_STEPS - 1);
            const float* px = x + ((size_t)tn * BATCH + bb + row) * IN_D + seg * 8;
            xm0 = *(const float4*)(px); xm1 = *(const float4*)(px + 4);
        }

        // ---- h-part MFMAs on top of accx ----
        float4v acc0 = accx0, acc1 = accx1;
#pragma unroll
        for (int ks = 0; ks < 16; ++ks) {
            short8 a = *(const short8*)(hfrag + FRAG_ADDR(ks * 64 + lane));
            if (ks & 1) acc1 = __builtin_amdgcn_mfma_f32_16x16x32_bf16(a, ufrag[ks], acc1, 0, 0, 0);
            else        acc0 = __builtin_amdgcn_mfma_f32_16x16x32_bf16(a, ufrag[ks], acc0, 0, 0, 0);
        }
        float4v acc = acc0 + acc1;
#pragma unroll
        for (int r = 0; r < 4; ++r)
            g_lds[wave * 256 + (lq * 4 + r) * 16 + lm] = acc[r];

        // ---- stage xfrag(t+1) from regs (readers drained at prev C) ----
        if (t + 1 < T_STEPS) {
            int fx = (seg >> 2) * 64 + (seg & 3) * 16 + row;
            *(short8*)(xfrag + FRAG_ADDR(fx)) = pack8(xn0, xn1);
            xn0 = xm0; xn1 = xm1;    // waits xm loads (compiler vmcnt)
        }

        lds_barrier();   // A: g_lds + xfrag visible; hfrag MFMA reads drained

        // ---- pointwise (fp32, c in register) ----
        float hv;
        {
            int hf2 = seg >> 4, nn = seg & 15;
            float fpre = g_lds[(0 * 2 + hf2) * 256 + row * 16 + nn];
            float ipre = g_lds[(1 * 2 + hf2) * 256 + row * 16 + nn];
            float opre = g_lds[(2 * 2 + hf2) * 256 + row * 16 + nn];
            float gpre = g_lds[(3 * 2 + hf2) * 256 + row * 16 + nn];
            float fv = sigm(fpre), iv = sigm(ipre), ov = sigm(opre);
            float gv = tanh_(gpre);
            c_reg = fv * c_reg + iv * gv;
            hv = ov * tanh_(c_reg);
        }
        out[((size_t)t * BATCH + bb + row) * HID + hbase + seg] = hv;  // plain cached

        if (t + 1 < T_STEPS) {
            // ---- publish h_t: [4 bf16 | tag | pad] per 16B, one coherent store ----
            {
                unsigned int bfv = f2bf(hv);
                unsigned int nb  = (unsigned int)__shfl_xor((int)bfv, 1);
                unsigned int p   = bfv | (nb << 16);          // valid on lanes with (lane&1)==0
                unsigned int q   = (unsigned int)__shfl_xor((int)p, 2);
                if ((lane & 3) == 0) {
                    int4v ch; ch[0] = (int)p; ch[1] = (int)q; ch[2] = t + 1; ch[3] = 0;
                    const unsigned char* pa = ex_wr + (size_t)(t & 1) * SLOT_BYTES;
                    asm volatile("global_store_dwordx4 %0, %1, off sc0 sc1"
                                 :: "v"(pa), "v"(ch) : "memory");
                }
            }

            // ---- accx for t+1 — overlaps our chunks' flight to the MALL ----
            accx0 = (float4v){bias, bias, bias, bias};
            accx1 = (float4v){0.f, 0.f, 0.f, 0.f};
#pragma unroll
            for (int ks = 0; ks < 8; ++ks) {
                short8 a = *(const short8*)(xfrag + FRAG_ADDR(ks * 64 + lane));
                if (ks & 1) accx1 = __builtin_amdgcn_mfma_f32_16x16x32_bf16(a, wfrag[ks], accx1, 0, 0, 0);
                else        accx0 = __builtin_amdgcn_mfma_f32_16x16x32_bf16(a, wfrag[ks], accx0, 0, 0, 0);
            }

            // ---- poll h_t: self-certified chunks, single round trip ----
            const unsigned char* pb = ex_rd + (size_t)(t & 1) * SLOT_BYTES;
            const int want = t + 1;
            int4v e0, e1, e2, e3;
            int guard = 0;
            for (;;) {
                asm volatile(
                    "global_load_dwordx4 %0, %4, off sc0 sc1\n\t"
                    "global_load_dwordx4 %1, %4, off offset:16 sc0 sc1\n\t"
                    "global_load_dwordx4 %2, %4, off offset:32 sc0 sc1\n\t"
                    "global_load_dwordx4 %3, %4, off offset:48 sc0 sc1\n\t"
                    "s_waitcnt vmcnt(0)"
                    : "=&v"(e0), "=&v"(e1), "=&v"(e2), "=&v"(e3)
                    : "v"(pb) : "memory");
                if ((e0[2] == want) & (e1[2] == want) & (e2[2] == want) & (e3[2] == want)) break;
                if (++guard > (1 << 20)) break;   // fail visibly rather than hang
            }
            // ---- unpack straight into hfrag (already bf16) ----
            int f0 = (seg >> 1) * 64 + (seg & 1) * 32 + row;
            int4v d0 = {e0[0], e0[1], e1[0], e1[1]};
            int4v d1 = {e2[0], e2[1], e3[0], e3[1]};
            *(int4v*)(hfrag + FRAG_ADDR(f0))      = d0;
            *(int4v*)(hfrag + FRAG_ADDR(f0 + 16)) = d1;

            lds_barrier();   // C: hfrag ready for next iteration's MFMAs
        } else {
            out_h[(size_t)(bb + row) * HID + hbase + seg] = hv;
            out_c[(size_t)(bb + row) * HID + hbase + seg] = c_reg;
        }
    }
}

extern "C" void kernel_launch(void* const* d_in, const int* in_sizes, int n_in,
                              void* d_out, int out_size, void* d_ws, size_t ws_size,
                              hipStream_t stream) {
    (void)in_sizes; (void)n_in; (void)out_size; (void)ws_size;
    const float* x   = (const float*)d_in[0];
    const float* h0  = (const float*)d_in[1];
    const float* c0  = (const float*)d_in[2];
    const float* Wf  = (const float*)d_in[3];
    const float* Wfb = (const float*)d_in[4];
    const float* Uf  = (const float*)d_in[5];
    const float* Ufb = (const float*)d_in[6];
    const float* Wi  = (const float*)d_in[7];
    const float* Wib = (const float*)d_in[8];
    const float* Ui  = (const float*)d_in[9];
    const float* Uib = (const float*)d_in[10];
    const float* Wo  = (const float*)d_in[11];
    const float* Wob = (const float*)d_in[12];
    const float* Uo  = (const float*)d_in[13];
    const float* Uob = (const float*)d_in[14];
    const float* Wc  = (const float*)d_in[15];
    const float* Wcb = (const float*)d_in[16];
    const float* Uc  = (const float*)d_in[17];
    const float* Ucb = (const float*)d_in[18];

    unsigned int* ws = (unsigned int*)d_ws;
    lstm_init_ws<<<(EXCH_INTS + 255) / 256, 256, 0, stream>>>(ws, EXCH_INTS);
    lstm_persist<<<NGROUP * NSLICE, THREADS, 0, stream>>>(
        x, h0, c0,
        Wf, Wfb, Uf, Ufb, Wi, Wib, Ui, Uib,
        Wo, Wob, Uo, Uob, Wc, Wcb, Uc, Ucb,
        (float*)d_out, (unsigned char*)d_ws);
}